// Round 13
// baseline (149.094 us; speedup 1.0000x reference)
//
#include <hip/hip_runtime.h>
#include <hip/hip_bf16.h>

typedef __attribute__((ext_vector_type(4))) float f32x4;
typedef __attribute__((ext_vector_type(8))) short s16x8;
typedef __attribute__((ext_vector_type(4))) short s16x4;

constexpr int S    = 2048;
constexpr int D    = 64;
constexpr int BH   = 32;        // B*H
constexpr int QBLK = 64;        // q rows per block (4 waves x 16)
constexpr int KBLK = 128;       // keys per compute phase (K/V tile)
constexpr int NSL  = S / KBLK;  // 16 iterations

__device__ __forceinline__ short bf16c(float f) {
  __hip_bfloat16 h = __float2bfloat16(f);   // single HW cvt (RNE)
  union { __hip_bfloat16 h; short s; } u; u.h = h;
  return u.s;
}

typedef const __attribute__((address_space(1))) unsigned int* as1_u32p;
typedef __attribute__((address_space(3))) unsigned int* as3_u32p;

// ============ pre-pass ============
// Kb: [bh][key][(ch ^ (key&7))*8] bf16 — row-major 128B key rows, chunk-swizzled.
// Vt: [bh][slice128][d][(c ^ (d&15))*8] bf16 — transposed, 256B d rows, chunk-swizzled.
__global__ __launch_bounds__(256) void prepass(const float* __restrict__ K,
                                               const float* __restrict__ V,
                                               short* __restrict__ Kb,
                                               short* __restrict__ Vt) {
  const int bid = blockIdx.x;
  const int tid = threadIdx.x;
  if (bid < BH * 32) {
    // ---- K convert: one block per (bh, 64-key slice) ----
    const int bh = bid >> 5, sl = bid & 31;
    const float* src = K + ((size_t)bh * S + (size_t)sl * 64) * D;
    short* dst = Kb + ((size_t)bh * S + (size_t)sl * 64) * D;
    #pragma unroll
    for (int c = 0; c < 2; ++c) {
      const int idx = tid * 2 + c;   // 0..511
      const int row = idx >> 3;      // key within slice
      const int ch  = idx & 7;       // d-chunk (8 floats)
      const float* s = src + row * D + ch * 8;
      f32x4 a = *(const f32x4*)s, b = *(const f32x4*)(s + 4);
      s16x8 o;
      #pragma unroll
      for (int j = 0; j < 4; ++j) { o[j] = bf16c(a[j]); o[4 + j] = bf16c(b[j]); }
      *(s16x8*)(dst + row * D + ((ch ^ (row & 7)) * 8)) = o;
    }
  } else {
    // ---- V transpose: one block per (bh, 128-key slice) ----
    __shared__ short tile[128][72];   // [key][d], padded
    const int b2 = bid - BH * 32;
    const int bh = b2 >> 4, sl = b2 & 15;
    const float* src = V + ((size_t)bh * S + (size_t)sl * 128) * D;
    {
      const int row = tid >> 1;          // key 0..127
      const int c0  = (tid & 1) * 32;    // 32 d-cols per thread
      #pragma unroll
      for (int q = 0; q < 8; ++q) {
        f32x4 a = *(const f32x4*)(src + row * D + c0 + q * 4);
        #pragma unroll
        for (int j = 0; j < 4; ++j) tile[row][c0 + q * 4 + j] = bf16c(a[j]);
      }
    }
    __syncthreads();
    short* dst = Vt + (size_t)bh * S * D + (size_t)sl * (D * KBLK);
    const int d = tid >> 2;              // 0..63
    #pragma unroll
    for (int cc = 0; cc < 4; ++cc) {
      const int c = (tid & 3) * 4 + cc;  // key-chunk 0..15
      s16x8 o;
      #pragma unroll
      for (int j = 0; j < 8; ++j) o[j] = tile[c * 8 + j][d];
      *(s16x8*)(dst + d * KBLK + ((c ^ (d & 15)) * 8)) = o;
    }
  }
}

// ============ main: R12 structure + non-temporal mask loads / O stores ============
__global__ __launch_bounds__(256, 4)
void attn_fwd13(const float* __restrict__ Qg, const short* __restrict__ Kb,
                const short* __restrict__ Vt, const float* __restrict__ Mg,
                float* __restrict__ Og) {
  __shared__ alignas(16) short K_lds[KBLK][64];     // 16 KB
  __shared__ alignas(16) short V_lds[D][KBLK];      // 16 KB
  __shared__ alignas(16) short P_lds[4][16][64];    // 8 KB, wave-private halves

  const int tid  = threadIdx.x;
  const int wave = tid >> 6;
  const int lane = tid & 63;
  const int lq   = lane & 15;
  const int g    = lane >> 4;

  const int bh = blockIdx.x & (BH - 1);
  const int qt = blockIdx.x / BH;
  const size_t base = (size_t)bh * S * D;
  const int    qrow = qt * QBLK + wave * 16 + lq;
  const float* mrow = Mg + ((size_t)bh * S + qrow) * S + g * 4;
  const int    rot  = (qt + bh) & (NSL - 1);   // per-block key-window rotation

  // Q fragment, pre-scaled by log2(e)/8
  s16x8 qf[2];
  {
    const float sc = 1.44269504088896340736f * 0.125f;
    const float* qp = Qg + base + (size_t)qrow * D + g * 8;
    #pragma unroll
    for (int h2 = 0; h2 < 2; ++h2) {
      f32x4 a = *(const f32x4*)(qp + h2 * 32);
      f32x4 b = *(const f32x4*)(qp + h2 * 32 + 4);
      #pragma unroll
      for (int j = 0; j < 4; ++j) {
        qf[h2][j]     = bf16c(a[j] * sc);
        qf[h2][4 + j] = bf16c(b[j] * sc);
      }
    }
  }

  f32x4 acc[4];
  #pragma unroll
  for (int dt = 0; dt < 4; ++dt) acc[dt] = (f32x4)0.0f;
  float m = -1e30f, lp = 0.0f;

  const char* kbase = (const char*)(Kb + base);
  const char* vbase = (const char*)(Vt + base);
  char* kl = (char*)&K_lds[0][0];
  char* vl = (char*)&V_lds[0][0];
  char* pl = (char*)&P_lds[wave][lq][0];

  #pragma unroll 1
  for (int it = 0; it < NSL; ++it) {
    const int ip = (it + rot) & (NSL - 1);   // physical key window (order-invariant)
    __syncthreads();   // previous iteration's LDS reads done
    {
      const char* ks = kbase + (size_t)ip * 16384;
      const char* vs = vbase + (size_t)ip * 16384;
      #pragma unroll
      for (int i = 0; i < 4; ++i) {
        __builtin_amdgcn_global_load_lds((as1_u32p)(ks + i * 4096 + tid * 16),
                                         (as3_u32p)(kl + i * 4096 + tid * 16), 16, 0, 0);
        __builtin_amdgcn_global_load_lds((as1_u32p)(vs + i * 4096 + tid * 16),
                                         (as3_u32p)(vl + i * 4096 + tid * 16), 16, 0, 0);
      }
    }
    // mask stripe (touch-once): NON-TEMPORAL loads — keep the 537MB stream out of L2
    // so the per-XCD K/V working set (~2MB) stays resident. Issued pre-barrier so the
    // barrier's vmcnt(0) drain absorbs the latency.
    f32x4 mk[8];
    {
      const float* mp = mrow + ip * KBLK;
      #pragma unroll
      for (int t = 0; t < 8; ++t)
        mk[t] = __builtin_nontemporal_load((const f32x4*)(mp + t * 16));
    }
    __syncthreads();   // tiles + mask landed

    #pragma unroll
    for (int h = 0; h < 2; ++h) {   // two 64-key halves
      // ---- swapped QK^T: rows = keys, cols = q ----
      f32x4 st[4];
      __builtin_amdgcn_s_setprio(1);
      #pragma unroll
      for (int t = 0; t < 4; ++t) {
        st[t] = (f32x4)0.0f;
        #pragma unroll
        for (int h2 = 0; h2 < 2; ++h2) {
          const s16x8 kf = *(const s16x8*)(kl + (h * 64 + t * 16 + lq) * 128 +
                                           (((h2 * 4 + g) ^ (lq & 7)) * 16));
          st[t] = __builtin_amdgcn_mfma_f32_16x16x32_bf16(kf, qf[h2], st[t], 0, 0, 0);
        }
      }
      __builtin_amdgcn_s_setprio(0);

      // ---- deferred-max online softmax (exp2 domain) ----
      float mx = st[0][0];
      #pragma unroll
      for (int t = 0; t < 4; ++t)
        #pragma unroll
        for (int r = 0; r < 4; ++r) mx = fmaxf(mx, st[t][r]);
      if (!__all(mx <= m + 8.0f)) {
        float rm = fmaxf(mx, __shfl_xor(mx, 16));
        rm = fmaxf(rm, __shfl_xor(rm, 32));
        const float mn  = fmaxf(m, rm);
        const float fac = __builtin_amdgcn_exp2f(m - mn);
        lp *= fac;
        #pragma unroll
        for (int dt = 0; dt < 4; ++dt)
          #pragma unroll
          for (int r = 0; r < 4; ++r) acc[dt][r] *= fac;
        m = mn;
      }
      float ps = 0.0f;
      #pragma unroll
      for (int t = 0; t < 4; ++t)
        #pragma unroll
        for (int r = 0; r < 4; ++r) {
          st[t][r] = __builtin_amdgcn_exp2f(st[t][r] - m);
          ps += st[t][r];
        }
      lp += ps;

      // ---- apply dropout mask, native-cvt pack, wave-private P stash (swizzled) ----
      #pragma unroll
      for (int t = 0; t < 4; ++t) {
        const f32x4 mkv = mk[h * 4 + t];
        s16x4 pk;
        #pragma unroll
        for (int r = 0; r < 4; ++r) pk[r] = bf16c(st[t][r] * mkv[r]);
        *(s16x4*)(pl + (((2 * t + (g >> 1)) ^ (lq & 7)) * 16) + (g & 1) * 8) = pk;
      }
      asm volatile("" ::: "memory");

      // ---- swapped PV: rows = d, cols = q ----
      __builtin_amdgcn_s_setprio(1);
      #pragma unroll
      for (int kk = 0; kk < 2; ++kk) {
        const s16x8 pf = *(const s16x8*)(pl + (((4 * kk + g) ^ (lq & 7)) * 16));
        #pragma unroll
        for (int dt = 0; dt < 4; ++dt) {
          const s16x8 vf = *(const s16x8*)(vl + (dt * 16 + lq) * 256 +
                                           (((h * 8 + kk * 4 + g) ^ lq) * 16));
          acc[dt] = __builtin_amdgcn_mfma_f32_16x16x32_bf16(vf, pf, acc[dt], 0, 0, 0);
        }
      }
      __builtin_amdgcn_s_setprio(0);
      asm volatile("" ::: "memory");
    }
  }

  // epilogue: reduce lane-partial denominator across the 4 g-groups
  float l = lp + __shfl_xor(lp, 16);
  l += __shfl_xor(l, 32);
  const float inv_l = 1.0f / l;
  float* op = Og + base + (size_t)qrow * D;
  #pragma unroll
  for (int dt = 0; dt < 4; ++dt) {
    f32x4 o;
    #pragma unroll
    for (int r = 0; r < 4; ++r) o[r] = acc[dt][r] * inv_l;
    __builtin_nontemporal_store(o, (f32x4*)(op + dt * 16 + g * 4));  // write-once
  }
}

// ============ fallback (round-1 kernel) if ws too small ============
__global__ __launch_bounds__(256, 4)
void attn_fwd_fb(const float* __restrict__ Qg, const float* __restrict__ Kg,
                 const float* __restrict__ Vg, const float* __restrict__ Mg,
                 float* __restrict__ Og) {
  __shared__ alignas(16) short Kl[32][72];
  __shared__ alignas(16) short Vl[D][40];
  __shared__ alignas(16) short Pl[4][16][40];
  const int tid = threadIdx.x, wave = tid >> 6, lane = tid & 63;
  const int lq = lane & 15, g = lane >> 4;
  const int bh = blockIdx.x & (BH - 1), qt = blockIdx.x / BH;
  const size_t base = (size_t)bh * S * D;
  const int qrow = qt * QBLK + wave * 16 + lq;
  const float* mrow = Mg + ((size_t)bh * S + qrow) * S;
  s16x8 qf[2];
  {
    const float sc = 1.44269504088896340736f * 0.125f;
    const float* qp = Qg + base + (size_t)qrow * D + g * 8;
    #pragma unroll
    for (int h = 0; h < 2; ++h) {
      f32x4 a = *(const f32x4*)(qp + h * 32);
      f32x4 b = *(const f32x4*)(qp + h * 32 + 4);
      #pragma unroll
      for (int j = 0; j < 4; ++j) { qf[h][j] = bf16c(a[j] * sc); qf[h][4 + j] = bf16c(b[j] * sc); }
    }
  }
  f32x4 acc[4];
  #pragma unroll
  for (int dt = 0; dt < 4; ++dt) acc[dt] = (f32x4)0.0f;
  float m = -1e30f, l = 0.0f;
  for (int kb = 0; kb < S; kb += 32) {
    f32x4 mk[2];
    #pragma unroll
    for (int t = 0; t < 2; ++t) mk[t] = *(const f32x4*)(mrow + kb + t * 16 + g * 4);
    __syncthreads();
    {
      const int row = tid >> 3, d0 = (tid & 7) * 8;
      const float* kp = Kg + base + (size_t)(kb + row) * D + d0;
      f32x4 a = *(const f32x4*)kp, b = *(const f32x4*)(kp + 4);
      s16x8 f;
      #pragma unroll
      for (int j = 0; j < 4; ++j) { f[j] = bf16c(a[j]); f[4 + j] = bf16c(b[j]); }
      *(s16x8*)&Kl[row][d0] = f;
    }
    {
      const int d = tid & 63, kk = (tid >> 6) * 8;
      const float* vp = Vg + base + (size_t)(kb + kk) * D + d;
      s16x8 f;
      #pragma unroll
      for (int j = 0; j < 8; ++j) f[j] = bf16c(vp[(size_t)j * D]);
      *(s16x8*)&Vl[d][kk] = f;
    }
    __syncthreads();
    f32x4 st[2];
    #pragma unroll
    for (int t = 0; t < 2; ++t) {
      st[t] = (f32x4)0.0f;
      #pragma unroll
      for (int h = 0; h < 2; ++h) {
        s16x8 kf = *(const s16x8*)&Kl[t * 16 + lq][h * 32 + g * 8];
        st[t] = __builtin_amdgcn_mfma_f32_16x16x32_bf16(kf, qf[h], st[t], 0, 0, 0);
      }
    }
    float mx = st[0][0];
    #pragma unroll
    for (int t = 0; t < 2; ++t)
      #pragma unroll
      for (int r = 0; r < 4; ++r) mx = fmaxf(mx, st[t][r]);
    mx = fmaxf(mx, __shfl_xor(mx, 16));
    mx = fmaxf(mx, __shfl_xor(mx, 32));
    const float mn = fmaxf(m, mx);
    const float fac = __builtin_amdgcn_exp2f(m - mn);
    float p[8], ps = 0.0f;
    #pragma unroll
    for (int t = 0; t < 2; ++t)
      #pragma unroll
      for (int r = 0; r < 4; ++r) { float e = __builtin_amdgcn_exp2f(st[t][r] - mn); p[t * 4 + r] = e; ps += e; }
    ps += __shfl_xor(ps, 16);
    ps += __shfl_xor(ps, 32);
    l = l * fac + ps; m = mn;
    #pragma unroll
    for (int dt = 0; dt < 4; ++dt)
      #pragma unroll
      for (int r = 0; r < 4; ++r) acc[dt][r] *= fac;
    #pragma unroll
    for (int t = 0; t < 2; ++t) {
      s16x4 pk;
      #pragma unroll
      for (int r = 0; r < 4; ++r) pk[r] = bf16c(p[t * 4 + r] * mk[t][r]);
      *(s16x4*)&Pl[wave][lq][t * 16 + g * 4] = pk;
    }
    asm volatile("" ::: "memory");
    s16x8 pf = *(const s16x8*)&Pl[wave][lq][g * 8];
    #pragma unroll
    for (int dt = 0; dt < 4; ++dt) {
      s16x8 vf = *(const s16x8*)&Vl[dt * 16 + lq][g * 8];
      acc[dt] = __builtin_amdgcn_mfma_f32_16x16x32_bf16(vf, pf, acc[dt], 0, 0, 0);
    }
  }
  const float inv_l = 1.0f / l;
  float* op = Og + base + (size_t)qrow * D;
  #pragma unroll
  for (int dt = 0; dt < 4; ++dt) {
    f32x4 o;
    #pragma unroll
    for (int r = 0; r < 4; ++r) o[r] = acc[dt][r] * inv_l;
    *(f32x4*)(op + dt * 16 + g * 4) = o;
  }
}

extern "C" void kernel_launch(void* const* d_in, const int* in_sizes, int n_in,
                              void* d_out, int out_size, void* d_ws, size_t ws_size,
                              hipStream_t stream) {
  const float* Q = (const float*)d_in[0];
  const float* K = (const float*)d_in[1];
  const float* V = (const float*)d_in[2];
  const float* M = (const float*)d_in[3];
  float* O = (float*)d_out;
  const size_t nKV = (size_t)BH * S * D;                 // 4.19M shorts each
  const size_t need = 2 * nKV * sizeof(short);           // ~16.8 MB
  if (ws_size >= need) {
    short* Kb = (short*)d_ws;
    short* Vt = Kb + nKV;
    prepass<<<BH * 32 + BH * 16, 256, 0, stream>>>(K, V, Kb, Vt);
    attn_fwd13<<<(S / QBLK) * BH, 256, 0, stream>>>(Q, Kb, Vt, M, O);
  } else {
    attn_fwd_fb<<<(S / QBLK) * BH, 256, 0, stream>>>(Q, K, V, M, O);
  }
}

// Round 14
// 142.690 us; speedup vs baseline: 1.0449x; 1.0449x over previous
//
#include <hip/hip_runtime.h>
#include <hip/hip_bf16.h>

typedef __attribute__((ext_vector_type(4))) float f32x4;
typedef __attribute__((ext_vector_type(8))) short s16x8;
typedef __attribute__((ext_vector_type(4))) short s16x4;

constexpr int S    = 2048;
constexpr int D    = 64;
constexpr int BH   = 32;        // B*H
constexpr int QBLK = 64;        // q rows per block (4 waves x 16)
constexpr int KBLK = 128;       // keys per compute phase (K/V tile)
constexpr int NSL  = S / KBLK;  // 16 iterations

__device__ __forceinline__ short bf16c(float f) {
  __hip_bfloat16 h = __float2bfloat16(f);   // single HW cvt (RNE)
  union { __hip_bfloat16 h; short s; } u; u.h = h;
  return u.s;
}

typedef const __attribute__((address_space(1))) unsigned int* as1_u32p;
typedef __attribute__((address_space(3))) unsigned int* as3_u32p;

// ============ pre-pass ============
// Kb: PERMUTED row order within each 64-key half so QK^T C-layout == PV B-layout:
//   LDS row-slot s (within 64) holds original key perm^-1; chunk-swizzle keyed by slot.
//   slot(row) = 32*(row>>5) + 16*((row>>2)&1) + 4*((row>>3)&3) + (row&3)
// Vt: [bh][slice128][d][(c ^ (d&15))*8] bf16 — transposed, keys in natural order.
__global__ __launch_bounds__(256) void prepass(const float* __restrict__ K,
                                               const float* __restrict__ V,
                                               short* __restrict__ Kb,
                                               short* __restrict__ Vt) {
  const int bid = blockIdx.x;
  const int tid = threadIdx.x;
  if (bid < BH * 32) {
    // ---- K convert: one block per (bh, 64-key slice) ----
    const int bh = bid >> 5, sl = bid & 31;
    const float* src = K + ((size_t)bh * S + (size_t)sl * 64) * D;
    short* dst = Kb + ((size_t)bh * S + (size_t)sl * 64) * D;
    #pragma unroll
    for (int c = 0; c < 2; ++c) {
      const int idx = tid * 2 + c;   // 0..511
      const int row = idx >> 3;      // source key within slice
      const int ch  = idx & 7;       // d-chunk (8 floats)
      const float* s = src + row * D + ch * 8;
      f32x4 a = *(const f32x4*)s, b = *(const f32x4*)(s + 4);
      s16x8 o;
      #pragma unroll
      for (int j = 0; j < 4; ++j) { o[j] = bf16c(a[j]); o[4 + j] = bf16c(b[j]); }
      // destination row-slot per the QK^T->PV permutation
      const int slot = 32 * (row >> 5) + 16 * ((row >> 2) & 1) +
                       4 * ((row >> 3) & 3) + (row & 3);
      *(s16x8*)(dst + slot * D + ((ch ^ (slot & 7)) * 8)) = o;
    }
  } else {
    // ---- V transpose: one block per (bh, 128-key slice), natural key order ----
    __shared__ short tile[128][72];   // [key][d], padded
    const int b2 = bid - BH * 32;
    const int bh = b2 >> 4, sl = b2 & 15;
    const float* src = V + ((size_t)bh * S + (size_t)sl * 128) * D;
    {
      const int row = tid >> 1;          // key 0..127
      const int c0  = (tid & 1) * 32;    // 32 d-cols per thread
      #pragma unroll
      for (int q = 0; q < 8; ++q) {
        f32x4 a = *(const f32x4*)(src + row * D + c0 + q * 4);
        #pragma unroll
        for (int j = 0; j < 4; ++j) tile[row][c0 + q * 4 + j] = bf16c(a[j]);
      }
    }
    __syncthreads();
    short* dst = Vt + (size_t)bh * S * D + (size_t)sl * (D * KBLK);
    const int d = tid >> 2;              // 0..63
    #pragma unroll
    for (int cc = 0; cc < 4; ++cc) {
      const int c = (tid & 3) * 4 + cc;  // key-chunk 0..15
      s16x8 o;
      #pragma unroll
      for (int j = 0; j < 8; ++j) o[j] = tile[c * 8 + j][d];
      *(s16x8*)(dst + d * KBLK + ((c ^ (d & 15)) * 8)) = o;
    }
  }
}

// ============ main: R12 structure, P fully in registers (no P_lds) ============
__global__ __launch_bounds__(256, 4)
void attn_fwd14(const float* __restrict__ Qg, const short* __restrict__ Kb,
                const short* __restrict__ Vt, const float* __restrict__ Mg,
                float* __restrict__ Og) {
  __shared__ alignas(16) short K_lds[KBLK][64];     // 16 KB
  __shared__ alignas(16) short V_lds[D][KBLK];      // 16 KB

  const int tid  = threadIdx.x;
  const int wave = tid >> 6;
  const int lane = tid & 63;
  const int lq   = lane & 15;
  const int g    = lane >> 4;

  const int bh = blockIdx.x & (BH - 1);
  const int qt = blockIdx.x / BH;
  const size_t base = (size_t)bh * S * D;
  const int    qrow = qt * QBLK + wave * 16 + lq;
  const float* mrow = Mg + ((size_t)bh * S + qrow) * S + g * 8;  // permuted: 8g base
  const int    rot  = (qt + bh) & (NSL - 1);   // per-block key-window rotation

  // Q fragment, pre-scaled by log2(e)/8
  s16x8 qf[2];
  {
    const float sc = 1.44269504088896340736f * 0.125f;
    const float* qp = Qg + base + (size_t)qrow * D + g * 8;
    #pragma unroll
    for (int h2 = 0; h2 < 2; ++h2) {
      f32x4 a = *(const f32x4*)(qp + h2 * 32);
      f32x4 b = *(const f32x4*)(qp + h2 * 32 + 4);
      #pragma unroll
      for (int j = 0; j < 4; ++j) {
        qf[h2][j]     = bf16c(a[j] * sc);
        qf[h2][4 + j] = bf16c(b[j] * sc);
      }
    }
  }

  f32x4 acc[4];
  #pragma unroll
  for (int dt = 0; dt < 4; ++dt) acc[dt] = (f32x4)0.0f;
  float m = -1e30f, lp = 0.0f;

  const char* kbase = (const char*)(Kb + base);
  const char* vbase = (const char*)(Vt + base);
  char* kl = (char*)&K_lds[0][0];
  char* vl = (char*)&V_lds[0][0];

  #pragma unroll 1
  for (int it = 0; it < NSL; ++it) {
    const int ip = (it + rot) & (NSL - 1);   // physical key window (order-invariant)
    __syncthreads();   // previous iteration's LDS reads done
    {
      const char* ks = kbase + (size_t)ip * 16384;
      const char* vs = vbase + (size_t)ip * 16384;
      #pragma unroll
      for (int i = 0; i < 4; ++i) {
        __builtin_amdgcn_global_load_lds((as1_u32p)(ks + i * 4096 + tid * 16),
                                         (as3_u32p)(kl + i * 4096 + tid * 16), 16, 0, 0);
        __builtin_amdgcn_global_load_lds((as1_u32p)(vs + i * 4096 + tid * 16),
                                         (as3_u32p)(vl + i * 4096 + tid * 16), 16, 0, 0);
      }
    }
    // mask stripe, permutation-aware offsets (same per-instruction coalescing:
    // 4 distinct 16B chunks per wave-instruction; t-pairs fill complementary gaps)
    f32x4 mk[8];
    {
      const float* mp = mrow + ip * KBLK;
      #pragma unroll
      for (int i = 0; i < 8; ++i)
        mk[i] = *(const f32x4*)(mp + (i >> 2) * 64 + ((i >> 1) & 1) * 32 + (i & 1) * 4);
    }
    __syncthreads();   // tiles + mask landed

    #pragma unroll
    for (int h = 0; h < 2; ++h) {   // two 64-key halves
      // ---- swapped QK^T on permuted K rows: st[t][r] = key h*64+32(t>>1)+8g+4(t&1)+r ----
      f32x4 st[4];
      __builtin_amdgcn_s_setprio(1);
      #pragma unroll
      for (int t = 0; t < 4; ++t) {
        st[t] = (f32x4)0.0f;
        #pragma unroll
        for (int h2 = 0; h2 < 2; ++h2) {
          const s16x8 kf = *(const s16x8*)(kl + (h * 64 + t * 16 + lq) * 128 +
                                           (((h2 * 4 + g) ^ (lq & 7)) * 16));
          st[t] = __builtin_amdgcn_mfma_f32_16x16x32_bf16(kf, qf[h2], st[t], 0, 0, 0);
        }
      }
      __builtin_amdgcn_s_setprio(0);

      // ---- deferred-max online softmax (exp2 domain) ----
      float mx = st[0][0];
      #pragma unroll
      for (int t = 0; t < 4; ++t)
        #pragma unroll
        for (int r = 0; r < 4; ++r) mx = fmaxf(mx, st[t][r]);
      if (!__all(mx <= m + 8.0f)) {
        float rm = fmaxf(mx, __shfl_xor(mx, 16));
        rm = fmaxf(rm, __shfl_xor(rm, 32));
        const float mn  = fmaxf(m, rm);
        const float fac = __builtin_amdgcn_exp2f(m - mn);
        lp *= fac;
        #pragma unroll
        for (int dt = 0; dt < 4; ++dt)
          #pragma unroll
          for (int r = 0; r < 4; ++r) acc[dt][r] *= fac;
        m = mn;
      }
      float ps = 0.0f;
      #pragma unroll
      for (int t = 0; t < 4; ++t)
        #pragma unroll
        for (int r = 0; r < 4; ++r) {
          st[t][r] = __builtin_amdgcn_exp2f(st[t][r] - m);
          ps += st[t][r];
        }
      lp += ps;

      // ---- mask + cvt in REGISTERS: pf(kk) = pack(st[2kk], st[2kk+1]) ----
      // ---- swapped PV: rows = d, cols = q ----
      __builtin_amdgcn_s_setprio(1);
      #pragma unroll
      for (int kk = 0; kk < 2; ++kk) {
        const f32x4 mka = mk[h * 4 + 2 * kk];
        const f32x4 mkb = mk[h * 4 + 2 * kk + 1];
        s16x8 pf;
        #pragma unroll
        for (int r = 0; r < 4; ++r) {
          pf[r]     = bf16c(st[2 * kk][r]     * mka[r]);
          pf[4 + r] = bf16c(st[2 * kk + 1][r] * mkb[r]);
        }
        #pragma unroll
        for (int dt = 0; dt < 4; ++dt) {
          const s16x8 vf = *(const s16x8*)(vl + (dt * 16 + lq) * 256 +
                                           (((h * 8 + kk * 4 + g) ^ lq) * 16));
          acc[dt] = __builtin_amdgcn_mfma_f32_16x16x32_bf16(vf, pf, acc[dt], 0, 0, 0);
        }
      }
      __builtin_amdgcn_s_setprio(0);
    }
  }

  // epilogue: reduce lane-partial denominator across the 4 g-groups
  float l = lp + __shfl_xor(lp, 16);
  l += __shfl_xor(l, 32);
  const float inv_l = 1.0f / l;
  float* op = Og + base + (size_t)qrow * D;
  #pragma unroll
  for (int dt = 0; dt < 4; ++dt) {
    f32x4 o;
    #pragma unroll
    for (int r = 0; r < 4; ++r) o[r] = acc[dt][r] * inv_l;
    *(f32x4*)(op + dt * 16 + g * 4) = o;
  }
}

// ============ fallback (round-1 kernel) if ws too small ============
__global__ __launch_bounds__(256, 4)
void attn_fwd_fb(const float* __restrict__ Qg, const float* __restrict__ Kg,
                 const float* __restrict__ Vg, const float* __restrict__ Mg,
                 float* __restrict__ Og) {
  __shared__ alignas(16) short Kl[32][72];
  __shared__ alignas(16) short Vl[D][40];
  __shared__ alignas(16) short Pl[4][16][40];
  const int tid = threadIdx.x, wave = tid >> 6, lane = tid & 63;
  const int lq = lane & 15, g = lane >> 4;
  const int bh = blockIdx.x & (BH - 1), qt = blockIdx.x / BH;
  const size_t base = (size_t)bh * S * D;
  const int qrow = qt * QBLK + wave * 16 + lq;
  const float* mrow = Mg + ((size_t)bh * S + qrow) * S;
  s16x8 qf[2];
  {
    const float sc = 1.44269504088896340736f * 0.125f;
    const float* qp = Qg + base + (size_t)qrow * D + g * 8;
    #pragma unroll
    for (int h = 0; h < 2; ++h) {
      f32x4 a = *(const f32x4*)(qp + h * 32);
      f32x4 b = *(const f32x4*)(qp + h * 32 + 4);
      #pragma unroll
      for (int j = 0; j < 4; ++j) { qf[h][j] = bf16c(a[j] * sc); qf[h][4 + j] = bf16c(b[j] * sc); }
    }
  }
  f32x4 acc[4];
  #pragma unroll
  for (int dt = 0; dt < 4; ++dt) acc[dt] = (f32x4)0.0f;
  float m = -1e30f, l = 0.0f;
  for (int kb = 0; kb < S; kb += 32) {
    f32x4 mk[2];
    #pragma unroll
    for (int t = 0; t < 2; ++t) mk[t] = *(const f32x4*)(mrow + kb + t * 16 + g * 4);
    __syncthreads();
    {
      const int row = tid >> 3, d0 = (tid & 7) * 8;
      const float* kp = Kg + base + (size_t)(kb + row) * D + d0;
      f32x4 a = *(const f32x4*)kp, b = *(const f32x4*)(kp + 4);
      s16x8 f;
      #pragma unroll
      for (int j = 0; j < 4; ++j) { f[j] = bf16c(a[j]); f[4 + j] = bf16c(b[j]); }
      *(s16x8*)&Kl[row][d0] = f;
    }
    {
      const int d = tid & 63, kk = (tid >> 6) * 8;
      const float* vp = Vg + base + (size_t)(kb + kk) * D + d;
      s16x8 f;
      #pragma unroll
      for (int j = 0; j < 8; ++j) f[j] = bf16c(vp[(size_t)j * D]);
      *(s16x8*)&Vl[d][kk] = f;
    }
    __syncthreads();
    f32x4 st[2];
    #pragma unroll
    for (int t = 0; t < 2; ++t) {
      st[t] = (f32x4)0.0f;
      #pragma unroll
      for (int h = 0; h < 2; ++h) {
        s16x8 kf = *(const s16x8*)&Kl[t * 16 + lq][h * 32 + g * 8];
        st[t] = __builtin_amdgcn_mfma_f32_16x16x32_bf16(kf, qf[h], st[t], 0, 0, 0);
      }
    }
    float mx = st[0][0];
    #pragma unroll
    for (int t = 0; t < 2; ++t)
      #pragma unroll
      for (int r = 0; r < 4; ++r) mx = fmaxf(mx, st[t][r]);
    mx = fmaxf(mx, __shfl_xor(mx, 16));
    mx = fmaxf(mx, __shfl_xor(mx, 32));
    const float mn = fmaxf(m, mx);
    const float fac = __builtin_amdgcn_exp2f(m - mn);
    float p[8], ps = 0.0f;
    #pragma unroll
    for (int t = 0; t < 2; ++t)
      #pragma unroll
      for (int r = 0; r < 4; ++r) { float e = __builtin_amdgcn_exp2f(st[t][r] - mn); p[t * 4 + r] = e; ps += e; }
    ps += __shfl_xor(ps, 16);
    ps += __shfl_xor(ps, 32);
    l = l * fac + ps; m = mn;
    #pragma unroll
    for (int dt = 0; dt < 4; ++dt)
      #pragma unroll
      for (int r = 0; r < 4; ++r) acc[dt][r] *= fac;
    #pragma unroll
    for (int t = 0; t < 2; ++t) {
      s16x4 pk;
      #pragma unroll
      for (int r = 0; r < 4; ++r) pk[r] = bf16c(p[t * 4 + r] * mk[t][r]);
      *(s16x4*)&Pl[wave][lq][t * 16 + g * 4] = pk;
    }
    asm volatile("" ::: "memory");
    s16x8 pf = *(const s16x8*)&Pl[wave][lq][g * 8];
    #pragma unroll
    for (int dt = 0; dt < 4; ++dt) {
      s16x8 vf = *(const s16x8*)&Vl[dt * 16 + lq][g * 8];
      acc[dt] = __builtin_amdgcn_mfma_f32_16x16x32_bf16(vf, pf, acc[dt], 0, 0, 0);
    }
  }
  const float inv_l = 1.0f / l;
  float* op = Og + base + (size_t)qrow * D;
  #pragma unroll
  for (int dt = 0; dt < 4; ++dt) {
    f32x4 o;
    #pragma unroll
    for (int r = 0; r < 4; ++r) o[r] = acc[dt][r] * inv_l;
    *(f32x4*)(op + dt * 16 + g * 4) = o;
  }
}

extern "C" void kernel_launch(void* const* d_in, const int* in_sizes, int n_in,
                              void* d_out, int out_size, void* d_ws, size_t ws_size,
                              hipStream_t stream) {
  const float* Q = (const float*)d_in[0];
  const float* K = (const float*)d_in[1];
  const float* V = (const float*)d_in[2];
  const float* M = (const float*)d_in[3];
  float* O = (float*)d_out;
  const size_t nKV = (size_t)BH * S * D;                 // 4.19M shorts each
  const size_t need = 2 * nKV * sizeof(short);           // ~16.8 MB
  if (ws_size >= need) {
    short* Kb = (short*)d_ws;
    short* Vt = Kb + nKV;
    prepass<<<BH * 32 + BH * 16, 256, 0, stream>>>(K, V, Kb, Vt);
    attn_fwd14<<<(S / QBLK) * BH, 256, 0, stream>>>(Q, Kb, Vt, M, O);
  } else {
    attn_fwd_fb<<<(S / QBLK) * BH, 256, 0, stream>>>(Q, K, V, M, O);
  }
}